// Round 1
// baseline (148.122 us; speedup 1.0000x reference)
//
#include <hip/hip_runtime.h>
#include <math.h>

namespace {
constexpr int B = 64, A = 5, H = 52, W = 52, T = 50;
constexpr int HW = H * W;        // 2704
constexpr int N = A * HW;        // 13520
constexpr int CH2 = 2 * A * HW;  // 27040 (per-batch xy/wh/weight span)
constexpr float POS_THRESH_F = 0.6f;
constexpr float EPS_F = 1e-5f;

// d_out layout: t_xy, t_wh, t_xywh_weight, t_o_obj, t_o_noobj, t_label (flat, f32)
constexpr long O_XY = 0;
constexpr long O_WH = (long)B * CH2;
constexpr long O_WT = 2L * B * CH2;
constexpr long O_OBJ = 3L * B * CH2;
constexpr long O_NOOBJ = O_OBJ + (long)B * N;
constexpr long O_LABEL = O_NOOBJ + (long)B * N;
}  // namespace

// Kernel 1: per predicted box, max IoU over 50 truths -> t_o_noobj mask;
// also writes the "base" values of all six outputs (copies / zeros / -1).
__global__ __launch_bounds__(256) void region_k1(
    const float* __restrict__ xy, const float* __restrict__ wh,
    const float* __restrict__ obj, const float* __restrict__ truth,
    const float* __restrict__ biases, float* __restrict__ out) {
#pragma clang fp contract(off)
  __shared__ float s_tl[T], s_tr[T], s_tt[T], s_tb[T], s_ta[T];
  const int b = blockIdx.y;
  const int tid = threadIdx.x;
  if (tid < T) {
    const float* t5 = truth + ((long)b * T + tid) * 5;
    const float tx = t5[0], ty = t5[1], tw = t5[2], th = t5[3];
    s_tl[tid] = tx - tw * 0.5f;
    s_tr[tid] = tx + tw * 0.5f;
    s_tt[tid] = ty - th * 0.5f;
    s_tb[tid] = ty + th * 0.5f;
    s_ta[tid] = tw * th;
  }
  __syncthreads();
  const int n = blockIdx.x * 256 + tid;
  if (n >= N) return;
  const int a = n / HW;
  const int r = n - a * HW;
  const int h = r / W;
  const int w = r - h * W;
  const long pb = (long)b * CH2;
  const long ix = pb + (long)a * HW + r;   // channel a (x / w-part)
  const long iy = ix + (long)A * HW;       // channel a+A (y / h-part)
  const float x = xy[ix], y = xy[iy];
  const float wx = wh[ix], wyv = wh[iy];
  const long io = (long)b * N + n;
  const float objv = obj[io];
  // box center/size — mirror reference f32 op order exactly
  const float bx = (x + (float)w) / (float)W;
  const float by = (y + (float)h) / (float)H;
  const float bw = expf(wx) * biases[2 * a] / (float)W;
  const float bh = expf(wyv) * biases[2 * a + 1] / (float)H;
  const float bl = bx - bw * 0.5f, brr = bx + bw * 0.5f;
  const float bt = by - bh * 0.5f, bbt = by + bh * 0.5f;
  const float barea = bw * bh;
  float m = -INFINITY;
  for (int t = 0; t < T; ++t) {
    float ow = fminf(brr, s_tr[t]) - fmaxf(bl, s_tl[t]);
    float oh = fminf(bbt, s_tb[t]) - fmaxf(bt, s_tt[t]);
    ow = fmaxf(ow, 0.0f);
    oh = fmaxf(oh, 0.0f);
    const float ov = ow * oh;
    const float iou = ov / ((barea + s_ta[t]) - ov);  // IEEE div, matches jnp
    m = fmaxf(m, iou);
  }
  out[O_NOOBJ + io] = (m > POS_THRESH_F) ? objv : 0.0f;
  out[O_OBJ + io] = objv;
  out[O_LABEL + io] = -1.0f;
  out[O_XY + ix] = x;
  out[O_XY + iy] = y;
  out[O_WH + ix] = wx;
  out[O_WH + iy] = wyv;
  out[O_WT + ix] = 0.0f;
  out[O_WT + iy] = 0.0f;
}

// Kernel 2: per-batch truth scatters with exact JAX .at[] semantics:
//  - negative index (-1) wraps to the last element (JAX normalizes before drop)
//  - lin1 with channel 2*tn+A >= 2A is genuinely OOB -> dropped
//  - duplicate targets: last write (ascending t) wins; scatter order preserved
__global__ __launch_bounds__(64) void region_k2(
    const float* __restrict__ xy, const float* __restrict__ wh,
    const float* __restrict__ obj, const float* __restrict__ truth,
    const float* __restrict__ biases, float* __restrict__ out) {
#pragma clang fp contract(off)
  __shared__ float s_vx[T], s_vy[T], s_vw[T], s_vh[T], s_vwt[T];
  __shared__ float s_vobj[T], s_vnoobj[T], s_cls[T];
  __shared__ int s_cell[T], s_eff[T], s_lin0[T], s_lin1[T], s_tn[T], s_win[T];
  const int b = blockIdx.x;
  const int t = threadIdx.x;
  if (t < T) {
    const float* t5 = truth + ((long)b * T + t) * 5;
    const float tx = t5[0], ty = t5[1], tw = t5[2], th = t5[3];
    s_cls[t] = t5[4];
    int ti = (int)(tx * (float)W);  // trunc, matches astype(int32)
    int tj = (int)(ty * (float)H);
    int tn = 0;
    float best = -INFINITY;
    for (int aa = 0; aa < A; ++aa) {
      const float bwa = biases[2 * aa] / (float)W;
      const float bha = biases[2 * aa + 1] / (float)H;
      const float num = fminf(tw, bwa) * fminf(th, bha);
      const float den = fmaxf(tw, bwa) * fmaxf(th, bha) + EPS_F;
      const float rr = num / den;
      if (rr > best) { best = rr; tn = aa; }  // first-max, like jnp.argmax
    }
    if (tw <= EPS_F || th <= EPS_F) { ti = -1; tj = -1; tn = -1; }
    const bool valid = ti >= 0;
    const int cell = valid ? (tn * H + tj) * W + ti : -1;
    s_cell[t] = cell;
    s_eff[t] = valid ? cell : (N - 1);  // -1 wraps to N-1 in winner scatter
    const int nc = tn < 0 ? 0 : tn, jc = tj < 0 ? 0 : tj, ic = ti < 0 ? 0 : ti;
    s_tn[t] = tn;
    s_lin0[t] = (2 * tn * H + tj) * W + ti;        // only used when win
    s_lin1[t] = ((2 * tn + A) * H + tj) * W + ti;  // only used when win
    s_vx[t] = tx * (float)W - (float)ic;
    s_vy[t] = ty * (float)H - (float)jc;
    s_vw[t] = logf(fmaxf(tw * (float)W / biases[2 * nc], 1e-12f));
    s_vh[t] = logf(fmaxf(th * (float)H / biases[2 * nc + 1], 1e-12f));
    s_vwt[t] = 2.0f - tw * th;  // COORD_SCALE = 1
    // v_obj = IoU of predicted box at (nc,jc,ic) vs this truth (RESCORE)
    const long rr2 = (long)nc * HW + (long)jc * W + ic;
    const long pb = (long)b * CH2;
    const float x = xy[pb + rr2], y = xy[pb + (long)A * HW + rr2];
    const float wx = wh[pb + rr2], wyv = wh[pb + (long)A * HW + rr2];
    s_vnoobj[t] = obj[(long)b * N + rr2];
    const float bx = (x + (float)ic) / (float)W;
    const float by = (y + (float)jc) / (float)H;
    const float bw = expf(wx) * biases[2 * nc] / (float)W;
    const float bh = expf(wyv) * biases[2 * nc + 1] / (float)H;
    float ow = fminf(bx + bw * 0.5f, tx + tw * 0.5f) -
               fmaxf(bx - bw * 0.5f, tx - tw * 0.5f);
    float oh = fminf(by + bh * 0.5f, ty + th * 0.5f) -
               fmaxf(by - bh * 0.5f, ty - th * 0.5f);
    ow = fmaxf(ow, 0.0f);
    oh = fmaxf(oh, 0.0f);
    const float ov = ow * oh;
    s_vobj[t] = ov / (((bw * bh) + tw * th) - ov);
  }
  __syncthreads();
  if (t < T) {
    int winf = 0;
    if (s_cell[t] >= 0) {  // valid
      winf = 1;
      for (int u = t + 1; u < T; ++u)
        if (s_eff[u] == s_cell[t]) { winf = 0; break; }  // higher t wins
    }
    s_win[t] = winf;
  }
  __syncthreads();
  if (t == 0) {
    float* oxy = out + O_XY + (long)b * CH2;
    float* owh = out + O_WH + (long)b * CH2;
    float* owt = out + O_WT + (long)b * CH2;
    float* oob = out + O_OBJ + (long)b * N;
    float* ono = out + O_NOOBJ + (long)b * N;
    float* olb = out + O_LABEL + (long)b * N;
    const int J = CH2 - 1;  // wrapped target of index -1 in 2A*H*W space
    // t_xy: scatter lin0 (vx) fully, then lin1 (vy) fully — reference order
    for (int u = 0; u < T; ++u) oxy[s_win[u] ? s_lin0[u] : J] = s_vx[u];
    for (int u = 0; u < T; ++u) {
      if (s_win[u]) {
        if (2 * s_tn[u] + A < 2 * A) oxy[s_lin1[u]] = s_vy[u];  // else dropped
      } else {
        oxy[J] = s_vy[u];  // -1 wraps
      }
    }
    // t_wh
    for (int u = 0; u < T; ++u) owh[s_win[u] ? s_lin0[u] : J] = s_vw[u];
    for (int u = 0; u < T; ++u) {
      if (s_win[u]) {
        if (2 * s_tn[u] + A < 2 * A) owh[s_lin1[u]] = s_vh[u];
      } else {
        owh[J] = s_vh[u];
      }
    }
    // t_xywh_weight
    for (int u = 0; u < T; ++u) owt[s_win[u] ? s_lin0[u] : J] = s_vwt[u];
    for (int u = 0; u < T; ++u) {
      if (s_win[u]) {
        if (2 * s_tn[u] + A < 2 * A) owt[s_lin1[u]] = s_vwt[u];
      } else {
        owt[J] = s_vwt[u];
      }
    }
    // obj-space scatters at dcell (win ? cell : N-1 via wrap)
    for (int u = 0; u < T; ++u) {
      const int idx = s_win[u] ? s_cell[u] : (N - 1);
      oob[idx] = s_vobj[u];
    }
    for (int u = 0; u < T; ++u) {
      const int idx = s_win[u] ? s_cell[u] : (N - 1);
      ono[idx] = s_vnoobj[u];
    }
    for (int u = 0; u < T; ++u) {
      const int idx = s_win[u] ? s_cell[u] : (N - 1);
      olb[idx] = s_cls[u];
    }
  }
}

extern "C" void kernel_launch(void* const* d_in, const int* in_sizes, int n_in,
                              void* d_out, int out_size, void* d_ws,
                              size_t ws_size, hipStream_t stream) {
  const float* xy = (const float*)d_in[0];
  const float* wh = (const float*)d_in[1];
  const float* obj = (const float*)d_in[2];
  const float* truth = (const float*)d_in[3];
  const float* biases = (const float*)d_in[4];
  float* out = (float*)d_out;
  dim3 g1((N + 255) / 256, B);
  region_k1<<<g1, 256, 0, stream>>>(xy, wh, obj, truth, biases, out);
  region_k2<<<B, 64, 0, stream>>>(xy, wh, obj, truth, biases, out);
}

// Round 2
// 108.133 us; speedup vs baseline: 1.3698x; 1.3698x over previous
//
#include <hip/hip_runtime.h>
#include <math.h>

namespace {
constexpr int B = 64, A = 5, H = 52, W = 52, T = 50;
constexpr int HW = H * W;        // 2704
constexpr int N = A * HW;        // 13520
constexpr int CH2 = 2 * A * HW;  // 27040 (per-batch xy/wh/weight span)
constexpr float POS_THRESH_F = 0.6f;
constexpr float EPS_F = 1e-5f;

// d_out layout: t_xy, t_wh, t_xywh_weight, t_o_obj, t_o_noobj, t_label (flat, f32)
constexpr long O_XY = 0;
constexpr long O_WH = (long)B * CH2;
constexpr long O_WT = 2L * B * CH2;
constexpr long O_OBJ = 3L * B * CH2;
constexpr long O_NOOBJ = O_OBJ + (long)B * N;
constexpr long O_LABEL = O_NOOBJ + (long)B * N;
}  // namespace

// Kernel 1: per predicted box, "any IoU > 0.6?" over 50 truths -> t_o_noobj
// mask; also writes the base values of all six outputs.
// Division-free threshold test (iou>0.6 <=> ov>0.375*(barea+ta)) with a
// conservative tolerance band; threads whose decision falls in the band
// (~none) rerun the exact IEEE-division loop so boundary decisions are
// bit-identical to the reference.
__global__ __launch_bounds__(256) void region_k1(
    const float* __restrict__ xy, const float* __restrict__ wh,
    const float* __restrict__ obj, const float* __restrict__ truth,
    const float* __restrict__ biases, float* __restrict__ out) {
#pragma clang fp contract(off)
  __shared__ float4 s_box[T];  // {tl, tt, tr, tb}
  __shared__ float s_ta375[T];
  __shared__ float s_ta[T];
  const int b = blockIdx.y;
  const int tid = threadIdx.x;
  if (tid < T) {
    const float* t5 = truth + ((long)b * T + tid) * 5;
    const float tx = t5[0], ty = t5[1], tw = t5[2], th = t5[3];
    s_box[tid] = make_float4(tx - tw * 0.5f, ty - th * 0.5f,
                             tx + tw * 0.5f, ty + th * 0.5f);
    const float ta = tw * th;
    s_ta[tid] = ta;
    s_ta375[tid] = 0.375f * ta;
  }
  __syncthreads();
  const int n = blockIdx.x * 256 + tid;
  if (n >= N) return;
  const int a = n / HW;
  const int r = n - a * HW;
  const int h = r / W;
  const int w = r - h * W;
  const long pb = (long)b * CH2;
  const long ix = pb + (long)a * HW + r;  // channel a (x / w-part)
  const long iy = ix + (long)A * HW;      // channel a+A (y / h-part)
  const float x = xy[ix], y = xy[iy];
  const float wx = wh[ix], wyv = wh[iy];
  const long io = (long)b * N + n;
  const float objv = obj[io];
  // box center/size — mirror reference f32 op order exactly
  const float bx = (x + (float)w) / (float)W;
  const float by = (y + (float)h) / (float)H;
  const float bw = expf(wx) * biases[2 * a] / (float)W;
  const float bh = expf(wyv) * biases[2 * a + 1] / (float)H;
  const float bl = bx - bw * 0.5f, brr = bx + bw * 0.5f;
  const float bt = by - bh * 0.5f, bbt = by + bh * 0.5f;
  const float barea = bw * bh;
  const float tb375 = 0.375f * barea;
  bool hit = false, nearb = false;
#pragma unroll 10
  for (int t = 0; t < T; ++t) {
    const float4 b4 = s_box[t];
    float ow = fminf(brr, b4.z) - fmaxf(bl, b4.x);
    float oh = fminf(bbt, b4.w) - fmaxf(bt, b4.y);
    ow = fmaxf(ow, 0.0f);
    oh = fmaxf(oh, 0.0f);
    const float ov = ow * oh;
    const float rhs = tb375 + s_ta375[t];  // 0.375*(barea+ta) (approx)
    const float dd = ov - rhs;
    const float tol = 2.6667e-5f * rhs;  // ~1e-5 * (barea+ta): >>2ulp band
    hit = hit || (dd > tol);
    nearb = nearb || (fabsf(dd) <= tol);
  }
  if (nearb && !hit) {
    // exact fallback — identical op sequence to the reference
    float m = -INFINITY;
    for (int t = 0; t < T; ++t) {
      const float4 b4 = s_box[t];
      float ow = fminf(brr, b4.z) - fmaxf(bl, b4.x);
      float oh = fminf(bbt, b4.w) - fmaxf(bt, b4.y);
      ow = fmaxf(ow, 0.0f);
      oh = fmaxf(oh, 0.0f);
      const float ov = ow * oh;
      const float iou = ov / ((barea + s_ta[t]) - ov);
      m = fmaxf(m, iou);
    }
    hit = m > POS_THRESH_F;
  }
  out[O_NOOBJ + io] = hit ? objv : 0.0f;
  out[O_OBJ + io] = objv;
  out[O_LABEL + io] = -1.0f;
  out[O_XY + ix] = x;
  out[O_XY + iy] = y;
  out[O_WH + ix] = wx;
  out[O_WH + iy] = wyv;
  out[O_WT + ix] = 0.0f;
  out[O_WT + iy] = 0.0f;
}

// Kernel 2: per-batch truth scatters with exact JAX .at[] semantics:
//  - negative index (-1) wraps to the last element (JAX normalizes before drop)
//  - lin1 with channel 2*tn+A >= 2A is genuinely OOB -> dropped
//  - duplicate targets: last write (ascending t, lin0-scatter before
//    lin1-scatter) wins — enforced via parallel "am I the last writer to my
//    address in the sequence?" checks instead of the old serial replay.
__global__ __launch_bounds__(128) void region_k2(
    const float* __restrict__ xy, const float* __restrict__ wh,
    const float* __restrict__ obj, const float* __restrict__ truth,
    const float* __restrict__ biases, float* __restrict__ out) {
#pragma clang fp contract(off)
  __shared__ float s_vx[T], s_vy[T], s_vw[T], s_vh[T], s_vwt[T];
  __shared__ float s_vobj[T], s_vnoobj[T], s_cls[T];
  __shared__ int s_cell[T], s_eff[T], s_lin0[T], s_lin1[T], s_tn[T], s_win[T];
  __shared__ int s_tgt2[2 * T];  // xy/wh/wt-plane scatter sequence (-2 = drop)
  __shared__ int s_tgtO[T];      // obj-plane scatter sequence
  const int b = blockIdx.x;
  const int t = threadIdx.x;
  if (t < T) {
    const float* t5 = truth + ((long)b * T + t) * 5;
    const float tx = t5[0], ty = t5[1], tw = t5[2], th = t5[3];
    s_cls[t] = t5[4];
    int ti = (int)(tx * (float)W);  // trunc, matches astype(int32)
    int tj = (int)(ty * (float)H);
    int tn = 0;
    float best = -INFINITY;
    for (int aa = 0; aa < A; ++aa) {
      const float bwa = biases[2 * aa] / (float)W;
      const float bha = biases[2 * aa + 1] / (float)H;
      const float num = fminf(tw, bwa) * fminf(th, bha);
      const float den = fmaxf(tw, bwa) * fmaxf(th, bha) + EPS_F;
      const float rr = num / den;
      if (rr > best) { best = rr; tn = aa; }  // first-max, like jnp.argmax
    }
    if (tw <= EPS_F || th <= EPS_F) { ti = -1; tj = -1; tn = -1; }
    const bool valid = ti >= 0;
    const int cell = valid ? (tn * H + tj) * W + ti : -1;
    s_cell[t] = cell;
    s_eff[t] = valid ? cell : (N - 1);  // -1 wraps to N-1 in winner scatter
    const int nc = tn < 0 ? 0 : tn, jc = tj < 0 ? 0 : tj, ic = ti < 0 ? 0 : ti;
    s_tn[t] = tn;
    s_lin0[t] = (2 * tn * H + tj) * W + ti;        // only used when win
    s_lin1[t] = ((2 * tn + A) * H + tj) * W + ti;  // only used when win
    s_vx[t] = tx * (float)W - (float)ic;
    s_vy[t] = ty * (float)H - (float)jc;
    s_vw[t] = logf(fmaxf(tw * (float)W / biases[2 * nc], 1e-12f));
    s_vh[t] = logf(fmaxf(th * (float)H / biases[2 * nc + 1], 1e-12f));
    s_vwt[t] = 2.0f - tw * th;  // COORD_SCALE = 1
    // v_obj = IoU of predicted box at (nc,jc,ic) vs this truth (RESCORE)
    const long rr2 = (long)nc * HW + (long)jc * W + ic;
    const long pb = (long)b * CH2;
    const float x = xy[pb + rr2], y = xy[pb + (long)A * HW + rr2];
    const float wx = wh[pb + rr2], wyv = wh[pb + (long)A * HW + rr2];
    s_vnoobj[t] = obj[(long)b * N + rr2];
    const float bx = (x + (float)ic) / (float)W;
    const float by = (y + (float)jc) / (float)H;
    const float bw = expf(wx) * biases[2 * nc] / (float)W;
    const float bh = expf(wyv) * biases[2 * nc + 1] / (float)H;
    float ow = fminf(bx + bw * 0.5f, tx + tw * 0.5f) -
               fmaxf(bx - bw * 0.5f, tx - tw * 0.5f);
    float oh = fminf(by + bh * 0.5f, ty + th * 0.5f) -
               fmaxf(by - bh * 0.5f, ty - th * 0.5f);
    ow = fmaxf(ow, 0.0f);
    oh = fmaxf(oh, 0.0f);
    const float ov = ow * oh;
    s_vobj[t] = ov / (((bw * bh) + tw * th) - ov);
  }
  __syncthreads();
  if (t < T) {
    int winf = 0;
    if (s_cell[t] >= 0) {  // valid
      winf = 1;
      for (int u = t + 1; u < T; ++u)
        if (s_eff[u] == s_cell[t]) { winf = 0; break; }  // higher t wins
    }
    s_win[t] = winf;
  }
  __syncthreads();
  if (t < T) {
    const int J = CH2 - 1;  // wrapped target of index -1 in 2A*H*W space
    int tgt0, tgt1;
    if (s_win[t]) {
      tgt0 = s_lin0[t];
      tgt1 = (2 * s_tn[t] + A < 2 * A) ? s_lin1[t] : -2;  // OOB -> dropped
    } else {
      tgt0 = J;  // -1 wraps
      tgt1 = J;
    }
    s_tgt2[t] = tgt0;
    s_tgt2[T + t] = tgt1;
    s_tgtO[t] = s_win[t] ? s_cell[t] : (N - 1);
  }
  __syncthreads();
  // xy/wh/wt planes: one 2T-item sequence, identical targets for all three
  if (t < 2 * T) {
    const int tg = s_tgt2[t];
    if (tg >= 0) {
      bool alive = true;
      for (int j = t + 1; j < 2 * T; ++j) alive &= (s_tgt2[j] != tg);
      if (alive) {
        const int u = (t < T) ? t : (t - T);
        const float vxy = (t < T) ? s_vx[u] : s_vy[u];
        const float vwh = (t < T) ? s_vw[u] : s_vh[u];
        out[O_XY + (long)b * CH2 + tg] = vxy;
        out[O_WH + (long)b * CH2 + tg] = vwh;
        out[O_WT + (long)b * CH2 + tg] = s_vwt[u];
      }
    }
  }
  // obj planes: one T-item sequence, identical targets for all three
  if (t < T) {
    const int tg = s_tgtO[t];
    bool alive = true;
    for (int j = t + 1; j < T; ++j) alive &= (s_tgtO[j] != tg);
    if (alive) {
      out[O_OBJ + (long)b * N + tg] = s_vobj[t];
      out[O_NOOBJ + (long)b * N + tg] = s_vnoobj[t];
      out[O_LABEL + (long)b * N + tg] = s_cls[t];
    }
  }
}

extern "C" void kernel_launch(void* const* d_in, const int* in_sizes, int n_in,
                              void* d_out, int out_size, void* d_ws,
                              size_t ws_size, hipStream_t stream) {
  const float* xy = (const float*)d_in[0];
  const float* wh = (const float*)d_in[1];
  const float* obj = (const float*)d_in[2];
  const float* truth = (const float*)d_in[3];
  const float* biases = (const float*)d_in[4];
  float* out = (float*)d_out;
  dim3 g1((N + 255) / 256, B);
  region_k1<<<g1, 256, 0, stream>>>(xy, wh, obj, truth, biases, out);
  region_k2<<<B, 128, 0, stream>>>(xy, wh, obj, truth, biases, out);
}